// Round 6
// baseline (5987.193 us; speedup 1.0000x reference)
//
#include <hip/hip_runtime.h>
#include <math.h>

#define HID   256
#define SEQ   512
#define BATCH 256
#define NPRED 64
#define NOUT  3
#define KP2   264    // fp16 k-pairs of padded xcat2: [x0,x1,x2,0, ctx(256), h(256), pad] / 2
#define GATES 1024

typedef unsigned int u32;
typedef _Float16 half2_t __attribute__((ext_vector_type(2)));
typedef __fp16   fp16x2_t __attribute__((ext_vector_type(2)));

__device__ __forceinline__ float sigmoidf_(float x) { return 1.0f / (1.0f + __expf(-x)); }
__device__ __forceinline__ float tanhf_(float x)    { return 1.0f - 2.0f / (__expf(2.0f * x) + 1.0f); }

// ---- fp16 pack / dot / pk helpers -----------------------------------------
__device__ __forceinline__ float fdot2_(u32 a, u32 b, float c) {
#if __has_builtin(__builtin_amdgcn_fdot2)
    union { u32 u; half2_t h; } x, y; x.u = a; y.u = b;
    return __builtin_amdgcn_fdot2(x.h, y.h, c, false);
#else
    union { u32 u; _Float16 h[2]; } x, y; x.u = a; y.u = b;
    return c + (float)x.h[0] * (float)y.h[0] + (float)x.h[1] * (float)y.h[1];
#endif
}
__device__ __forceinline__ u32 pkrtz_(float a, float b) {
#if __has_builtin(__builtin_amdgcn_cvt_pkrtz)
    union { fp16x2_t h; u32 u; } c; c.h = __builtin_amdgcn_cvt_pkrtz(a, b); return c.u;
#else
    union { _Float16 h[2]; u32 u; } c; c.h[0] = (_Float16)a; c.h[1] = (_Float16)b; return c.u;
#endif
}
__device__ __forceinline__ u32 pkrne_(float a, float b) {   // RNE pack
    union { _Float16 h[2]; u32 u; } c; c.h[0] = (_Float16)a; c.h[1] = (_Float16)b; return c.u;
}
__device__ __forceinline__ u32 pkfma_(u32 a, u32 b, u32 c) {  // v_pk_fma_f16
    union { u32 u; half2_t h; } x, y, z, r; x.u = a; y.u = b; z.u = c;
    r.h = x.h * y.h + z.h;
    return r.u;
}
__device__ __forceinline__ u32 pkadd_(u32 a, u32 b) {
    union { u32 u; half2_t h; } x, y, r; x.u = a; y.u = b;
    r.h = x.h + y.h;
    return r.u;
}
__device__ __forceinline__ float lof_(u32 u) {
    union { u32 x; half2_t h; } c; c.x = u; return (float)c.h[0];
}
__device__ __forceinline__ float hif_(u32 u) {
    union { u32 x; half2_t h; } c; c.x = u; return (float)c.h[1];
}

// ---------------------------------------------------------------------------
// prep_wc: Wcat column for padded-xcat2 k:
//   k<3: W_ih[:,k] (x_in) | k==3: 0 | 4<=k<260: W_ih[:,k-1] (ctx) |
//   260<=k<516: W_hh[:,k-260] (h) | else 0.  fp16 pairs, comp q = gate 4j+q.
// ---------------------------------------------------------------------------
__device__ __forceinline__ float colval_(const float* W_ih, const float* W_hh, int g, int k) {
    if (k < 3)   return W_ih[g * 259 + k];
    if (k == 3)  return 0.f;
    if (k < 260) return W_ih[g * 259 + (k - 1)];
    if (k < 516) return W_hh[g * HID + (k - 260)];
    return 0.f;
}
__global__ void prep_wc(const float* __restrict__ W_ih,
                        const float* __restrict__ W_hh,
                        uint4* __restrict__ Wc2) {
    const int p = blockIdx.x;        // 0..263 k-pair
    const int j = threadIdx.x;       // 0..255
    u32 comp[4];
    #pragma unroll
    for (int q = 0; q < 4; ++q) {
        const int g = 4 * j + q;
        comp[q] = pkrne_(colval_(W_ih, W_hh, g, 2 * p),
                         colval_(W_ih, W_hh, g, 2 * p + 1));
    }
    Wc2[p * 256 + j] = make_uint4(comp[0], comp[1], comp[2], comp[3]);
}

// ---------------------------------------------------------------------------
// prep_ma: MaT[k][j] = sum_m Wa[m][k]*Ua[m][j]; fp16 pairs.
// ---------------------------------------------------------------------------
__global__ void prep_ma(const float* __restrict__ Wa,
                        const float* __restrict__ Ua,
                        uint2* __restrict__ Ma2) {
    const int k4 = blockIdx.x;       // 0..63
    const int j  = threadIdx.x;      // 0..255
    float acc[4] = {0.f, 0.f, 0.f, 0.f};
    for (int m = 0; m < HID; ++m) {
        const float ua = Ua[m * HID + j];
        #pragma unroll
        for (int q = 0; q < 4; ++q)
            acc[q] += Wa[m * HID + 4 * k4 + q] * ua;
    }
    Ma2[k4 * 256 + j] = make_uint2(pkrne_(acc[0], acc[1]), pkrne_(acc[2], acc[3]));
}

__global__ void prep_misc(const float* __restrict__ b_ih,
                          const float* __restrict__ b_hh,
                          const float* __restrict__ ba,
                          const float* __restrict__ Ua,
                          float* __restrict__ bias_g,
                          float* __restrict__ v0) {
    const int t = threadIdx.x;
    if (t < GATES) bias_g[t] = b_ih[t] + b_hh[t];
    if (t < HID) {
        float acc = 0.f;
        for (int m = 0; m < HID; ++m) acc += ba[m] * Ua[m * HID + t];
        v0[t] = acc;
    }
}

// ---- P1: vq[j] = v0[j] + sum_k MaT[k][j] h[k]; fp16 dot2, 256 threads -----
__device__ __forceinline__ void p1_body(const uint2* __restrict__ Ma2,
                                        const float* __restrict__ v0,
                                        const u32* s_xh, u32* s_vqh, int j) {
    float a0 = 0.f, a1 = 0.f;
    #pragma unroll 8
    for (int p2 = 0; p2 < 64; ++p2) {
        const uint2 ma = Ma2[(p2 << 8) + j];
        const uint2 hh = *(const uint2*)&s_xh[130 + (p2 << 1)];
        a0 = fdot2_(ma.x, hh.x, a0);
        a1 = fdot2_(ma.y, hh.y, a1);
    }
    float acc = v0[j] + a0 + a1;
    const float accN = __shfl_xor(acc, 1);
    if (!(j & 1)) s_vqh[j >> 1] = pkrtz_(acc, accN);
}

// ---------------------------------------------------------------------------
// Persistent decoder: one 1024-thread block per batch element, 5 barriers/step.
// enc slice (512x256 fp16 = 256 KB) held ENTIRELY in registers.
// Gate GEMV h-part (Eh): per-wave global_load_lds DMA ring (4x1KB), manually
// vmcnt-paced, interleaved into phase A's register compute. Wave w streams
// rows [130+32*(w>>2) .. +31], j-quarter (w&3). Flash-style wave-local softmax
// removes the block-max barrier.
// ---------------------------------------------------------------------------
__global__ __launch_bounds__(1024)
void decoder_kernel(const float* __restrict__ enc,     // [B,S,H] fp32
                    const float* __restrict__ h0,
                    const float* __restrict__ c0,
                    const float* __restrict__ Wo,      // [3,H]
                    const float* __restrict__ bo,      // [3]
                    const uint2* __restrict__ Ma2,     // [64][256]
                    const float* __restrict__ v0,      // [256]
                    const uint4* __restrict__ Wc2,     // [264][256]
                    const float* __restrict__ bias_g,  // [1024]
                    float* __restrict__ pred_out,      // [B,N,3]
                    float* __restrict__ hid_out,       // [B,H]
                    float* __restrict__ attn_out)      // [B,N,S]
{
    const int b    = blockIdx.x;
    const int t    = threadIdx.x;
    const int wave = t >> 6;
    const int lane = t & 63;
    const int rg   = t >> 4;          // 0..63 row group (8 rows each)
    const int hc   = t & 15;          // 0..15 h-chunk (16 cols = 8 pairs)
    const int jj   = t & 255;         // j index for gate slices

    __shared__ __align__(16) float s_h[HID], s_c[HID];
    __shared__ __align__(16) u32   s_vqh[HID / 2];     // vq fp16 pairs
    __shared__ __align__(16) u32   s_xh[KP2];          // xcat2 fp16 pairs
    __shared__ __align__(16) float s_gp[8192];         // slices: Ec 0..3, Eh 4..7;
                                                       // first 2KB doubles as ctx partials
    __shared__ __align__(16) float s_scores[SEQ];      // raw e (wave-max relative)
    __shared__ __align__(16) u32   s_ehb[16 * 1024];   // 64KB: per-wave 4KB DMA ring
    __shared__ __align__(16) float s_wmax[16], s_wsum[16], s_pred[4];
    u32* const s_gpu = (u32*)s_gp;

    // Eh streaming geometry
    const u32* wcu   = (const u32*)Wc2;
    const int  ks_eh = wave >> 2;                      // 0..3 k-slice
    const int  prow  = 130 + (ks_eh << 5);             // first Wc2 row of slice
    const size_t srcb = ((size_t)prow << 10) + ((size_t)(wave & 3) << 8) + (lane << 2);

    // ---- load enc slice into registers (once), fp32 -> fp16 RNE ----
    u32 encR[64];
    {
        const float* ep = enc + ((size_t)b * SEQ + rg * 8) * HID + hc * 16;
        #pragma unroll
        for (int rr = 0; rr < 8; ++rr) {
            #pragma unroll
            for (int i2 = 0; i2 < 4; ++i2) {
                const float4 f = *(const float4*)(ep + rr * HID + i2 * 4);
                encR[rr * 8 + i2 * 2]     = pkrne_(f.x, f.y);
                encR[rr * 8 + i2 * 2 + 1] = pkrne_(f.z, f.w);
            }
        }
    }

    // ---- init LDS state ----
    if (t < HID) {
        const float hv = h0[b * HID + t];
        s_h[t] = hv;
        s_c[t] = c0[b * HID + t];
        const float hN = __shfl_xor(hv, 1);
        if (!(t & 1)) s_xh[130 + (t >> 1)] = pkrtz_(hv, hN);
    }
    if (t < 2) s_xh[t] = 0u;                       // SOS x_in pairs
    if (t >= 258 && t < KP2) s_xh[t] = 0u;         // zero pad pairs
    if (t < 4) s_pred[t] = 0.f;
    __syncthreads();

    // ---- prologue: vq for step 0 ----
    if (wave >= 4 && wave < 8) p1_body(Ma2, v0, s_xh, s_vqh, jj);
    __syncthreads();

#if __has_builtin(__builtin_amdgcn_global_load_lds)
  #define EH_ISSUE(c)                                                           \
    __builtin_amdgcn_global_load_lds(                                           \
        (const __attribute__((address_space(1))) u32*)(wcu + srcb + ((size_t)(c) << 10)), \
        (__attribute__((address_space(3))) u32*)&s_ehb[(wave << 10) + (((c) & 3) << 8)],  \
        16, 0, 0)
  #define EH_WAIT(W) asm volatile("s_waitcnt vmcnt(" #W ")" ::: "memory");      \
                     __builtin_amdgcn_sched_barrier(0)
  #define EH_STEP(c, W) {                                                       \
    EH_WAIT(W);                                                                 \
    const uint4 wv = *(const uint4*)&s_ehb[(wave << 10) + (((c) & 3) << 8) + (lane << 2)]; \
    const u32 xv = s_xh[prow + (c)];                                            \
    geh.x = fdot2_(wv.x, xv, geh.x);                                            \
    geh.y = fdot2_(wv.y, xv, geh.y);                                            \
    geh.z = fdot2_(wv.z, xv, geh.z);                                            \
    geh.w = fdot2_(wv.w, xv, geh.w);                                            \
    if ((c) + 4 < 32) { EH_ISSUE((c) + 4); }                                    \
  }
  #define EH_PROLOGUE EH_ISSUE(0); EH_ISSUE(1); EH_ISSUE(2); EH_ISSUE(3);
#else
  // fallback: direct L2 loads, no DMA
  #define EH_STEP(c, W) {                                                       \
    const uint4 wv = Wc2[((prow + (c)) << 8) + jj];                             \
    const u32 xv = s_xh[prow + (c)];                                            \
    geh.x = fdot2_(wv.x, xv, geh.x);                                            \
    geh.y = fdot2_(wv.y, xv, geh.y);                                            \
    geh.z = fdot2_(wv.z, xv, geh.z);                                            \
    geh.w = fdot2_(wv.w, xv, geh.w);                                            \
  }
  #define EH_PROLOGUE
#endif

#define ABLK(rr) {                                                              \
    float a = 0.f;                                                              \
    a = fdot2_(encR[(rr)*8+0], vq[0], a); a = fdot2_(encR[(rr)*8+1], vq[1], a); \
    a = fdot2_(encR[(rr)*8+2], vq[2], a); a = fdot2_(encR[(rr)*8+3], vq[3], a); \
    a = fdot2_(encR[(rr)*8+4], vq[4], a); a = fdot2_(encR[(rr)*8+5], vq[5], a); \
    a = fdot2_(encR[(rr)*8+6], vq[6], a); a = fdot2_(encR[(rr)*8+7], vq[7], a); \
    a += __shfl_xor(a, 1); a += __shfl_xor(a, 2);                               \
    a += __shfl_xor(a, 4); a += __shfl_xor(a, 8);                               \
    acc[rr] = a;                                                                \
  }

    for (int n = 0; n < NPRED; ++n) {
        // ================= [ACEh] scores + wave-softmax + ctx partials,
        //                   with Eh weight stream interleaved =================
        float4 geh = {0.f, 0.f, 0.f, 0.f};
        float  acc[8];
        {
            u32 vq[8];
            *(uint4*)&vq[0] = *(const uint4*)&s_vqh[hc * 8];
            *(uint4*)&vq[4] = *(const uint4*)&s_vqh[hc * 8 + 4];
            EH_PROLOGUE
            ABLK(0) EH_STEP(0, 3)  EH_STEP(1, 3)  EH_STEP(2, 3)  EH_STEP(3, 3)
            ABLK(1) EH_STEP(4, 3)  EH_STEP(5, 3)  EH_STEP(6, 3)  EH_STEP(7, 3)
            ABLK(2) EH_STEP(8, 3)  EH_STEP(9, 3)  EH_STEP(10, 3) EH_STEP(11, 3)
            ABLK(3) EH_STEP(12, 3) EH_STEP(13, 3) EH_STEP(14, 3) EH_STEP(15, 3)
            ABLK(4) EH_STEP(16, 3) EH_STEP(17, 3) EH_STEP(18, 3) EH_STEP(19, 3)
            ABLK(5) EH_STEP(20, 3) EH_STEP(21, 3) EH_STEP(22, 3) EH_STEP(23, 3)
            ABLK(6) EH_STEP(24, 3) EH_STEP(25, 3) EH_STEP(26, 3) EH_STEP(27, 3)
            ABLK(7) EH_STEP(28, 3) EH_STEP(29, 2) EH_STEP(30, 1) EH_STEP(31, 0)
        }
        // wave max (32 rows per wave)
        float mx = acc[0];
        #pragma unroll
        for (int rr = 1; rr < 8; ++rr) mx = fmaxf(mx, acc[rr]);
        mx = fmaxf(mx, __shfl_xor(mx, 16));
        mx = fmaxf(mx, __shfl_xor(mx, 32));
        if (lane == 0) s_wmax[wave] = mx;

        // exp relative to WAVE max; wave sum; stash raw e for attn
        {
            float e[8];
            #pragma unroll
            for (int rr = 0; rr < 8; ++rr) e[rr] = __expf(acc[rr] - mx);
            float su = e[0];
            #pragma unroll
            for (int rr = 1; rr < 8; ++rr) su += e[rr];
            su += __shfl_xor(su, 16);
            su += __shfl_xor(su, 32);
            if (lane == 0) s_wsum[wave] = su;
            if (hc == 0) {
                #pragma unroll
                for (int rr = 0; rr < 8; ++rr) s_scores[rg * 8 + rr] = e[rr];
            }
            // unnormalized ctx partials (fp16 pairs)
            u32 ah[8];
            #pragma unroll
            for (int i = 0; i < 8; ++i) ah[i] = 0u;
            #pragma unroll
            for (int rr = 0; rr < 8; ++rr) {
                const u32 wp = pkrne_(e[rr], e[rr]);
                #pragma unroll
                for (int i = 0; i < 8; ++i)
                    ah[i] = pkfma_(encR[rr * 8 + i], wp, ah[i]);
            }
            #pragma unroll
            for (int i = 0; i < 8; ++i) {
                u32 v = ah[i];
                v = pkadd_(v, (u32)__shfl_xor((int)v, 16));
                v = pkadd_(v, (u32)__shfl_xor((int)v, 32));
                ah[i] = v;
            }
            if ((lane >> 4) == 0) {
                *(uint4*)&s_gpu[wave * 128 + hc * 8]     = *(const uint4*)&ah[0];
                *(uint4*)&s_gpu[wave * 128 + hc * 8 + 4] = *(const uint4*)&ah[4];
            }
        }
        // Eh gate partial out (slice 4+ks)
        *(float4*)&s_gp[((4 + ks_eh) << 10) + (jj << 2)] = geh;
        __syncthreads();                                     // b3

        // ================= [D] global max/L, ctx combine, attn, x_in ========
        float M;
        {
            const float4* q4 = (const float4*)s_wmax;
            float4 v = q4[0];
            M = fmaxf(fmaxf(v.x, v.y), fmaxf(v.z, v.w));
            #pragma unroll
            for (int w = 1; w < 4; ++w) {
                v = q4[w];
                M = fmaxf(M, fmaxf(fmaxf(v.x, v.y), fmaxf(v.z, v.w)));
            }
        }
        float L = 0.f;
        #pragma unroll
        for (int w = 0; w < 16; ++w)
            L += __expf(s_wmax[w] - M) * s_wsum[w];
        const float invL = 1.0f / L;
        if (t < 128) {
            float cx = 0.f, cy = 0.f;
            #pragma unroll
            for (int w = 0; w < 16; ++w) {
                const float f = __expf(s_wmax[w] - M);
                const u32 u = s_gpu[w * 128 + t];
                cx += f * lof_(u);
                cy += f * hif_(u);
            }
            s_xh[2 + t] = pkrne_(cx * invL, cy * invL);
        }
        if (hc == 0) {
            const float fo = __expf(mx - M) * invL;
            float* ap = attn_out + ((size_t)b * NPRED + n) * SEQ + rg * 8;
            float4 o0, o1;
            o0.x = s_scores[rg*8+0] * fo; o0.y = s_scores[rg*8+1] * fo;
            o0.z = s_scores[rg*8+2] * fo; o0.w = s_scores[rg*8+3] * fo;
            o1.x = s_scores[rg*8+4] * fo; o1.y = s_scores[rg*8+5] * fo;
            o1.z = s_scores[rg*8+6] * fo; o1.w = s_scores[rg*8+7] * fo;
            *(float4*)ap = o0; *(float4*)(ap + 4) = o1;
        }
        if (t == 256) {
            s_xh[0] = pkrtz_(s_pred[0], s_pred[1]);
            s_xh[1] = pkrtz_(s_pred[2], 0.f);
        }
        __syncthreads();                                     // b4

        // ================= [Ec] gate partials, x_in+ctx pairs 0..129 ========
        {
            const int ks = t >> 8;
            const int pbeg = (ks < 2) ? 33 * ks : 66 + 32 * (ks - 2);
            const int pend = pbeg + ((ks < 2) ? 33 : 32);
            float4 g4 = {0.f, 0.f, 0.f, 0.f};
            #pragma unroll 4
            for (int p = pbeg; p < pend; ++p) {
                const uint4 w = Wc2[(p << 8) + jj];
                const u32 x = s_xh[p];
                g4.x = fdot2_(w.x, x, g4.x);
                g4.y = fdot2_(w.y, x, g4.y);
                g4.z = fdot2_(w.z, x, g4.z);
                g4.w = fdot2_(w.w, x, g4.w);
            }
            *(float4*)&s_gp[(ks << 10) + (jj << 2)] = g4;
        }
        __syncthreads();                                     // b5

        // ================= [F] gates finalize (8 slices) + LSTM =============
        if (t < HID) {
            float gv[4];
            #pragma unroll
            for (int q = 0; q < 4; ++q) {
                const int gi = (q << 8) + t;
                gv[q] = bias_g[gi]
                      + s_gp[gi]        + s_gp[1024 + gi]
                      + s_gp[2048 + gi] + s_gp[3072 + gi]
                      + s_gp[4096 + gi] + s_gp[5120 + gi]
                      + s_gp[6144 + gi] + s_gp[7168 + gi];
            }
            const float cn = sigmoidf_(gv[1]) * s_c[t] + sigmoidf_(gv[0]) * tanhf_(gv[2]);
            const float hn = sigmoidf_(gv[3]) * tanhf_(cn);
            s_c[t] = cn;
            s_h[t] = hn;
            const float hN = __shfl_xor(hn, 1);
            if (!(t & 1)) s_xh[130 + (t >> 1)] = pkrtz_(hn, hN);
        }
        __syncthreads();                                     // b6

        // ================= [G] pred (waves 0-2) || vq p1 (waves 4-7) ========
        if (wave < NOUT) {
            const float4 w4 = *(const float4*)&Wo[wave * HID + (lane << 2)];
            const float4 h4 = *(const float4*)&s_h[lane << 2];
            float p = w4.x * h4.x + w4.y * h4.y + w4.z * h4.z + w4.w * h4.w;
            #pragma unroll
            for (int off = 32; off >= 1; off >>= 1) p += __shfl_xor(p, off);
            if (lane == 0) {
                p += bo[wave];
                s_pred[wave] = p;
                pred_out[((size_t)b * NPRED + n) * NOUT + wave] = p;
            }
        } else if (wave >= 4 && wave < 8) {
            if (n + 1 < NPRED) p1_body(Ma2, v0, s_xh, s_vqh, jj);
        }
        __syncthreads();                                     // b7
    }

    if (t < HID) hid_out[b * HID + t] = s_h[t];
}

// ---------------------------------------------------------------------------
extern "C" void kernel_launch(void* const* d_in, const int* in_sizes, int n_in,
                              void* d_out, int out_size, void* d_ws, size_t ws_size,
                              hipStream_t stream) {
    const float* enc  = (const float*)d_in[0];
    const float* h0   = (const float*)d_in[1];
    const float* c0   = (const float*)d_in[2];
    const float* Wa   = (const float*)d_in[3];
    const float* ba   = (const float*)d_in[4];
    const float* Ua   = (const float*)d_in[5];
    // d_in[6] = bua: dropped — its score contribution is constant over s (softmax-invariant)
    const float* W_ih = (const float*)d_in[7];
    const float* W_hh = (const float*)d_in[8];
    const float* b_ih = (const float*)d_in[9];
    const float* b_hh = (const float*)d_in[10];
    const float* Wo   = (const float*)d_in[11];
    const float* bo   = (const float*)d_in[12];

    char* ws = (char*)d_ws;
    uint4* Wc2    = (uint4*)ws;                      ws += (size_t)KP2 * 256 * 16;  // 1,081,344
    uint2* Ma2    = (uint2*)ws;                      ws += (size_t)64 * 256 * 8;    //   131,072
    float* v0     = (float*)ws;                      ws += 256 * 4;
    float* bias_g = (float*)ws;                      ws += GATES * 4;
    (void)ws_size;

    float* pred_out = (float*)d_out;                    // [B,N,3]
    float* hid_out  = pred_out + BATCH * NPRED * NOUT;  // [1,B,H]
    float* attn_out = hid_out + BATCH * HID;            // [B,N,S]

    prep_wc  <<<dim3(KP2), dim3(256),  0, stream>>>(W_ih, W_hh, Wc2);
    prep_ma  <<<dim3(64),  dim3(256),  0, stream>>>(Wa, Ua, Ma2);
    prep_misc<<<dim3(1),   dim3(1024), 0, stream>>>(b_ih, b_hh, ba, Ua, bias_g, v0);
    decoder_kernel<<<dim3(BATCH), dim3(1024), 0, stream>>>(
        enc, h0, c0, Wo, bo, Ma2, v0, Wc2, bias_g,
        pred_out, hid_out, attn_out);
}

// Round 7
// 1355.586 us; speedup vs baseline: 4.4167x; 4.4167x over previous
//
#include <hip/hip_runtime.h>
#include <math.h>

#define HID   256
#define SEQ   512
#define BATCH 256
#define NPRED 64
#define NOUT  3
#define KP2   264    // fp16 k-pairs of padded xcat2: [x0,x1,x2,0, ctx(256), h(256), pad] / 2
#define GATES 1024

typedef unsigned int u32;
typedef _Float16 half2_t __attribute__((ext_vector_type(2)));
typedef __fp16   fp16x2_t __attribute__((ext_vector_type(2)));

__device__ __forceinline__ float sigmoidf_(float x) { return 1.0f / (1.0f + __expf(-x)); }
__device__ __forceinline__ float tanhf_(float x)    { return 1.0f - 2.0f / (__expf(2.0f * x) + 1.0f); }

// ---- fp16 pack / dot / pk helpers -----------------------------------------
__device__ __forceinline__ float fdot2_(u32 a, u32 b, float c) {
#if __has_builtin(__builtin_amdgcn_fdot2)
    union { u32 u; half2_t h; } x, y; x.u = a; y.u = b;
    return __builtin_amdgcn_fdot2(x.h, y.h, c, false);
#else
    union { u32 u; _Float16 h[2]; } x, y; x.u = a; y.u = b;
    return c + (float)x.h[0] * (float)y.h[0] + (float)x.h[1] * (float)y.h[1];
#endif
}
__device__ __forceinline__ u32 pkrtz_(float a, float b) {
#if __has_builtin(__builtin_amdgcn_cvt_pkrtz)
    union { fp16x2_t h; u32 u; } c; c.h = __builtin_amdgcn_cvt_pkrtz(a, b); return c.u;
#else
    union { _Float16 h[2]; u32 u; } c; c.h[0] = (_Float16)a; c.h[1] = (_Float16)b; return c.u;
#endif
}
__device__ __forceinline__ u32 pkrne_(float a, float b) {   // RNE pack
    union { _Float16 h[2]; u32 u; } c; c.h[0] = (_Float16)a; c.h[1] = (_Float16)b; return c.u;
}
__device__ __forceinline__ u32 pkfma_(u32 a, u32 b, u32 c) {  // v_pk_fma_f16
    union { u32 u; half2_t h; } x, y, z, r; x.u = a; y.u = b; z.u = c;
    r.h = x.h * y.h + z.h;
    return r.u;
}
__device__ __forceinline__ u32 pkadd_(u32 a, u32 b) {
    union { u32 u; half2_t h; } x, y, r; x.u = a; y.u = b;
    r.h = x.h + y.h;
    return r.u;
}
__device__ __forceinline__ float lof_(u32 u) {
    union { u32 x; half2_t h; } c; c.x = u; return (float)c.h[0];
}
__device__ __forceinline__ float hif_(u32 u) {
    union { u32 x; half2_t h; } c; c.x = u; return (float)c.h[1];
}

// ---------------------------------------------------------------------------
// prep_wc: Wcat column for padded-xcat2 k:
//   k<3: W_ih[:,k] (x_in) | k==3: 0 | 4<=k<260: W_ih[:,k-1] (ctx) |
//   260<=k<516: W_hh[:,k-260] (h) | else 0.  fp16 pairs, comp q = gate 4j+q.
// ---------------------------------------------------------------------------
__device__ __forceinline__ float colval_(const float* W_ih, const float* W_hh, int g, int k) {
    if (k < 3)   return W_ih[g * 259 + k];
    if (k == 3)  return 0.f;
    if (k < 260) return W_ih[g * 259 + (k - 1)];
    if (k < 516) return W_hh[g * HID + (k - 260)];
    return 0.f;
}
__global__ void prep_wc(const float* __restrict__ W_ih,
                        const float* __restrict__ W_hh,
                        uint4* __restrict__ Wc2) {
    const int p = blockIdx.x;        // 0..263 k-pair
    const int j = threadIdx.x;       // 0..255
    u32 comp[4];
    #pragma unroll
    for (int q = 0; q < 4; ++q) {
        const int g = 4 * j + q;
        comp[q] = pkrne_(colval_(W_ih, W_hh, g, 2 * p),
                         colval_(W_ih, W_hh, g, 2 * p + 1));
    }
    Wc2[p * 256 + j] = make_uint4(comp[0], comp[1], comp[2], comp[3]);
}

// ---------------------------------------------------------------------------
// prep_ma: MaT[k][j] = sum_m Wa[m][k]*Ua[m][j]; fp16 pairs.
// ---------------------------------------------------------------------------
__global__ void prep_ma(const float* __restrict__ Wa,
                        const float* __restrict__ Ua,
                        uint2* __restrict__ Ma2) {
    const int k4 = blockIdx.x;       // 0..63
    const int j  = threadIdx.x;      // 0..255
    float acc[4] = {0.f, 0.f, 0.f, 0.f};
    for (int m = 0; m < HID; ++m) {
        const float ua = Ua[m * HID + j];
        #pragma unroll
        for (int q = 0; q < 4; ++q)
            acc[q] += Wa[m * HID + 4 * k4 + q] * ua;
    }
    Ma2[k4 * 256 + j] = make_uint2(pkrne_(acc[0], acc[1]), pkrne_(acc[2], acc[3]));
}

__global__ void prep_misc(const float* __restrict__ b_ih,
                          const float* __restrict__ b_hh,
                          const float* __restrict__ ba,
                          const float* __restrict__ Ua,
                          float* __restrict__ bias_g,
                          float* __restrict__ v0) {
    const int t = threadIdx.x;
    if (t < GATES) bias_g[t] = b_ih[t] + b_hh[t];
    if (t < HID) {
        float acc = 0.f;
        for (int m = 0; m < HID; ++m) acc += ba[m] * Ua[m * HID + t];
        v0[t] = acc;
    }
}

// ---- P1: vq[j] = v0[j] + sum_k MaT[k][j] h[k]; Ma resident in LDS ---------
__device__ __forceinline__ void p1_body(const u32* s_ma,
                                        const float* __restrict__ v0,
                                        const u32* s_xh, u32* s_vqh, int j) {
    float a0 = 0.f, a1 = 0.f;
    #pragma unroll 8
    for (int p2 = 0; p2 < 64; ++p2) {
        const uint2 ma = *(const uint2*)&s_ma[(p2 << 9) + (j << 1)];
        const uint2 hh = *(const uint2*)&s_xh[130 + (p2 << 1)];
        a0 = fdot2_(ma.x, hh.x, a0);
        a1 = fdot2_(ma.y, hh.y, a1);
    }
    float acc = v0[j] + a0 + a1;
    const float accN = __shfl_xor(acc, 1);
    if (!(j & 1)) s_vqh[j >> 1] = pkrtz_(acc, accN);
}

// ---- Eh: gate partial over h-part k-pairs 130..257; 2-way split-K ---------
__device__ __forceinline__ void eh_body(const uint4* __restrict__ Wc2,
                                        const u32* s_xh, float* s_gp,
                                        int j, int ks2) {
    float4 g4 = {0.f, 0.f, 0.f, 0.f};
    const int pbeg = 130 + (ks2 << 6);
    #pragma unroll 4
    for (int pp = 0; pp < 64; ++pp) {
        const int p = pbeg + pp;
        const uint4 w = Wc2[(p << 8) + j];
        const u32 x = s_xh[p];
        g4.x = fdot2_(w.x, x, g4.x);
        g4.y = fdot2_(w.y, x, g4.y);
        g4.z = fdot2_(w.z, x, g4.z);
        g4.w = fdot2_(w.w, x, g4.w);
    }
    *(float4*)&s_gp[((4 + ks2) << 10) + (j << 2)] = g4;
}

// ---------------------------------------------------------------------------
// Persistent decoder: one 1024-thread block per batch element, 5 barriers/step.
// enc slice (512x256 fp16 = 256 KB) held ENTIRELY in registers.
// Ma (128 KB) held resident in LDS (copied once) -> p1 reads the LDS port,
// not the contended L2 path.  Flash-style wave-local softmax (exp vs wave
// max, global max folded into D) removes one barrier.  Eh (gate h-part)
// runs in phase G on waves 8-15 (R5 structure).  c-state in registers.
// All unrolls bounded <=8 (full unrolls spill encR: R4/R6 regressions).
// ---------------------------------------------------------------------------
__global__ __launch_bounds__(1024)
void decoder_kernel(const float* __restrict__ enc,     // [B,S,H] fp32
                    const float* __restrict__ h0,
                    const float* __restrict__ c0,
                    const float* __restrict__ Wo,      // [3,H]
                    const float* __restrict__ bo,      // [3]
                    const uint2* __restrict__ Ma2,     // [64][256]
                    const float* __restrict__ v0,      // [256]
                    const uint4* __restrict__ Wc2,     // [264][256]
                    const float* __restrict__ bias_g,  // [1024]
                    float* __restrict__ pred_out,      // [B,N,3]
                    float* __restrict__ hid_out,       // [B,H]
                    float* __restrict__ attn_out)      // [B,N,S]
{
    const int b    = blockIdx.x;
    const int t    = threadIdx.x;
    const int wave = t >> 6;
    const int lane = t & 63;
    const int rg   = t >> 4;          // 0..63 row group (8 rows each)
    const int hc   = t & 15;          // 0..15 h-chunk (16 cols = 8 pairs)
    const int jj   = t & 255;         // j index for gate slices

    __shared__ __align__(16) float s_h[HID];
    __shared__ __align__(16) u32   s_vqh[HID / 2];     // vq fp16 pairs
    __shared__ __align__(16) u32   s_xh[KP2];          // xcat2 fp16 pairs
    __shared__ __align__(16) float s_gp[6144];         // C: u32[16][128] (overlaps Ec slices);
                                                       // gate slices: Ec 0..3, Eh 4..5
    __shared__ __align__(16) float s_scores[SEQ];      // raw e (wave-max relative)
    __shared__ __align__(16) u32   s_ma[32768];        // Ma resident: 128 KB
    __shared__ __align__(16) float s_wmax[16], s_wsum[16], s_pred[4];
    u32* const s_gpu = (u32*)s_gp;

    // ---- load enc slice into registers (once), fp32 -> fp16 RNE ----
    u32 encR[64];
    {
        const float* ep = enc + ((size_t)b * SEQ + rg * 8) * HID + hc * 16;
        #pragma unroll
        for (int rr = 0; rr < 8; ++rr) {
            #pragma unroll
            for (int i2 = 0; i2 < 4; ++i2) {
                const float4 f = *(const float4*)(ep + rr * HID + i2 * 4);
                encR[rr * 8 + i2 * 2]     = pkrne_(f.x, f.y);
                encR[rr * 8 + i2 * 2 + 1] = pkrne_(f.z, f.w);
            }
        }
    }

    // ---- copy Ma2 global -> LDS (once) ----
    {
        const uint4* g4 = (const uint4*)Ma2;
        uint4* l4 = (uint4*)s_ma;
        #pragma unroll
        for (int i = 0; i < 8; ++i) l4[t + (i << 10)] = g4[t + (i << 10)];
    }

    // ---- init LDS state; c-state in registers (thread t<256 owns c[t]) ----
    float cR = 0.f;
    if (t < HID) {
        const float hv = h0[b * HID + t];
        s_h[t] = hv;
        cR = c0[b * HID + t];
        const float hN = __shfl_xor(hv, 1);
        if (!(t & 1)) s_xh[130 + (t >> 1)] = pkrtz_(hv, hN);
    }
    if (t < 2) s_xh[t] = 0u;                       // SOS x_in pairs
    if (t >= 258 && t < KP2) s_xh[t] = 0u;         // zero pad pairs
    if (t < 4) s_pred[t] = 0.f;
    __syncthreads();

    // ---- prologue: vq + Eh partials for step 0 ----
    if (wave >= 4 && wave < 8)      p1_body(s_ma, v0, s_xh, s_vqh, jj);
    else if (wave >= 8)             eh_body(Wc2, s_xh, s_gp, jj, (t >> 8) - 2);
    __syncthreads();

    for (int n = 0; n < NPRED; ++n) {
        // ---- [AC] scores + wave-local softmax + ctx partials ----
        float acc[8];
        {
            u32 vq[8];
            *(uint4*)&vq[0] = *(const uint4*)&s_vqh[hc * 8];
            *(uint4*)&vq[4] = *(const uint4*)&s_vqh[hc * 8 + 4];
            #pragma unroll
            for (int rr = 0; rr < 8; ++rr) {
                float a = 0.f;
                #pragma unroll
                for (int i = 0; i < 8; ++i) a = fdot2_(encR[rr * 8 + i], vq[i], a);
                acc[rr] = a;
            }
        }
        // reduce across the 16 h-chunk lanes (offsets 1..8)
        #pragma unroll
        for (int rr = 0; rr < 8; ++rr) {
            acc[rr] += __shfl_xor(acc[rr], 1);
            acc[rr] += __shfl_xor(acc[rr], 2);
            acc[rr] += __shfl_xor(acc[rr], 4);
            acc[rr] += __shfl_xor(acc[rr], 8);
        }
        // wave max (32 rows per wave)
        float mx = acc[0];
        #pragma unroll
        for (int rr = 1; rr < 8; ++rr) mx = fmaxf(mx, acc[rr]);
        mx = fmaxf(mx, __shfl_xor(mx, 16));
        mx = fmaxf(mx, __shfl_xor(mx, 32));
        if (lane == 0) s_wmax[wave] = mx;

        // exp relative to WAVE max; wave sum; stash raw e; ctx partials
        {
            float e[8];
            #pragma unroll
            for (int rr = 0; rr < 8; ++rr) e[rr] = __expf(acc[rr] - mx);
            float su = e[0];
            #pragma unroll
            for (int rr = 1; rr < 8; ++rr) su += e[rr];
            su += __shfl_xor(su, 16);
            su += __shfl_xor(su, 32);
            if (lane == 0) s_wsum[wave] = su;
            if (hc == 0) {
                #pragma unroll
                for (int rr = 0; rr < 8; ++rr) s_scores[rg * 8 + rr] = e[rr];
            }
            u32 ah[8];
            #pragma unroll
            for (int i = 0; i < 8; ++i) ah[i] = 0u;
            #pragma unroll
            for (int rr = 0; rr < 8; ++rr) {
                const u32 wp = pkrne_(e[rr], e[rr]);   // raw weights; scaling in D
                #pragma unroll
                for (int i = 0; i < 8; ++i)
                    ah[i] = pkfma_(encR[rr * 8 + i], wp, ah[i]);
            }
            #pragma unroll
            for (int i = 0; i < 8; ++i) {
                u32 v = ah[i];
                v = pkadd_(v, (u32)__shfl_xor((int)v, 16));
                v = pkadd_(v, (u32)__shfl_xor((int)v, 32));
                ah[i] = v;
            }
            if ((lane >> 4) == 0) {
                *(uint4*)&s_gpu[wave * 128 + hc * 8]     = *(const uint4*)&ah[0];
                *(uint4*)&s_gpu[wave * 128 + hc * 8 + 4] = *(const uint4*)&ah[4];
            }
        }
        __syncthreads();                                     // b3

        // ---- [D] global max/L; ctx combine + pack; attn out; x_in pairs ----
        float M;
        {
            const float4* q4 = (const float4*)s_wmax;
            float4 v = q4[0];
            M = fmaxf(fmaxf(v.x, v.y), fmaxf(v.z, v.w));
            #pragma unroll
            for (int w = 1; w < 4; ++w) {
                v = q4[w];
                M = fmaxf(M, fmaxf(fmaxf(v.x, v.y), fmaxf(v.z, v.w)));
            }
        }
        float L = 0.f;
        #pragma unroll
        for (int w = 0; w < 16; ++w)
            L += __expf(s_wmax[w] - M) * s_wsum[w];
        const float invL = 1.0f / L;
        if (t < 128) {
            float cx = 0.f, cy = 0.f;
            #pragma unroll
            for (int w = 0; w < 16; ++w) {
                const float f = __expf(s_wmax[w] - M);
                const u32 u = s_gpu[w * 128 + t];
                cx += f * lof_(u);
                cy += f * hif_(u);
            }
            s_xh[2 + t] = pkrne_(cx * invL, cy * invL);
        }
        if (hc == 0) {
            const float fo = __expf(mx - M) * invL;
            float* ap = attn_out + ((size_t)b * NPRED + n) * SEQ + rg * 8;
            float4 o0, o1;
            o0.x = s_scores[rg*8+0] * fo; o0.y = s_scores[rg*8+1] * fo;
            o0.z = s_scores[rg*8+2] * fo; o0.w = s_scores[rg*8+3] * fo;
            o1.x = s_scores[rg*8+4] * fo; o1.y = s_scores[rg*8+5] * fo;
            o1.z = s_scores[rg*8+6] * fo; o1.w = s_scores[rg*8+7] * fo;
            *(float4*)ap = o0; *(float4*)(ap + 4) = o1;
        }
        if (t == 256) {
            s_xh[0] = pkrtz_(s_pred[0], s_pred[1]);
            s_xh[1] = pkrtz_(s_pred[2], 0.f);
        }
        __syncthreads();                                     // b4

        // ---- [Ec] gate partials over x_in+ctx k-pairs 0..129; 4-way split ----
        {
            const int ks = t >> 8;
            const int pbeg = (ks < 2) ? 33 * ks : 66 + 32 * (ks - 2);
            const int pend = pbeg + ((ks < 2) ? 33 : 32);
            float4 g4 = {0.f, 0.f, 0.f, 0.f};
            #pragma unroll 4
            for (int p = pbeg; p < pend; ++p) {
                const uint4 w = Wc2[(p << 8) + jj];
                const u32 x = s_xh[p];
                g4.x = fdot2_(w.x, x, g4.x);
                g4.y = fdot2_(w.y, x, g4.y);
                g4.z = fdot2_(w.z, x, g4.z);
                g4.w = fdot2_(w.w, x, g4.w);
            }
            *(float4*)&s_gp[(ks << 10) + (jj << 2)] = g4;
        }
        __syncthreads();                                     // b5

        // ---- [F] gates finalize (6 slices) + LSTM pointwise; pack new h ----
        if (t < HID) {
            float gv[4];
            #pragma unroll
            for (int q = 0; q < 4; ++q) {
                const int gi = (q << 8) + t;
                gv[q] = bias_g[gi] + s_gp[gi] + s_gp[1024 + gi]
                      + s_gp[2048 + gi] + s_gp[3072 + gi]
                      + s_gp[4096 + gi] + s_gp[5120 + gi];
            }
            const float cn = sigmoidf_(gv[1]) * cR + sigmoidf_(gv[0]) * tanhf_(gv[2]);
            const float hn = sigmoidf_(gv[3]) * tanhf_(cn);
            cR = cn;
            s_h[t] = hn;
            const float hN = __shfl_xor(hn, 1);
            if (!(t & 1)) s_xh[130 + (t >> 1)] = pkrtz_(hn, hN);
        }
        __syncthreads();                                     // b6

        // ---- [G] pred (waves 0-2) || vq p1 from LDS (waves 4-7) || Eh (8-15) ----
        if (wave < NOUT) {
            const float4 w4 = *(const float4*)&Wo[wave * HID + (lane << 2)];
            const float4 h4 = *(const float4*)&s_h[lane << 2];
            float p = w4.x * h4.x + w4.y * h4.y + w4.z * h4.z + w4.w * h4.w;
            #pragma unroll
            for (int off = 32; off >= 1; off >>= 1) p += __shfl_xor(p, off);
            if (lane == 0) {
                p += bo[wave];
                s_pred[wave] = p;
                pred_out[((size_t)b * NPRED + n) * NOUT + wave] = p;
            }
        } else if (wave >= 4 && wave < 8) {
            if (n + 1 < NPRED) p1_body(s_ma, v0, s_xh, s_vqh, jj);
        } else if (wave >= 8) {
            if (n + 1 < NPRED) eh_body(Wc2, s_xh, s_gp, jj, (t >> 8) - 2);
        }
        __syncthreads();                                     // b7
    }

    if (t < HID) hid_out[b * HID + t] = s_h[t];
}

// ---------------------------------------------------------------------------
extern "C" void kernel_launch(void* const* d_in, const int* in_sizes, int n_in,
                              void* d_out, int out_size, void* d_ws, size_t ws_size,
                              hipStream_t stream) {
    const float* enc  = (const float*)d_in[0];
    const float* h0   = (const float*)d_in[1];
    const float* c0   = (const float*)d_in[2];
    const float* Wa   = (const float*)d_in[3];
    const float* ba   = (const float*)d_in[4];
    const float* Ua   = (const float*)d_in[5];
    // d_in[6] = bua: dropped — its score contribution is constant over s (softmax-invariant)
    const float* W_ih = (const float*)d_in[7];
    const float* W_hh = (const float*)d_in[8];
    const float* b_ih = (const float*)d_in[9];
    const float* b_hh = (const float*)d_in[10];
    const float* Wo   = (const float*)d_in[11];
    const float* bo   = (const float*)d_in[12];

    char* ws = (char*)d_ws;
    uint4* Wc2    = (uint4*)ws;                      ws += (size_t)KP2 * 256 * 16;  // 1,081,344
    uint2* Ma2    = (uint2*)ws;                      ws += (size_t)64 * 256 * 8;    //   131,072
    float* v0     = (float*)ws;                      ws += 256 * 4;
    float* bias_g = (float*)ws;                      ws += GATES * 4;
    (void)ws_size;

    float* pred_out = (float*)d_out;                    // [B,N,3]
    float* hid_out  = pred_out + BATCH * NPRED * NOUT;  // [1,B,H]
    float* attn_out = hid_out + BATCH * HID;            // [B,N,S]

    prep_wc  <<<dim3(KP2), dim3(256),  0, stream>>>(W_ih, W_hh, Wc2);
    prep_ma  <<<dim3(64),  dim3(256),  0, stream>>>(Wa, Ua, Ma2);
    prep_misc<<<dim3(1),   dim3(1024), 0, stream>>>(b_ih, b_hh, ba, Ua, bias_g, v0);
    decoder_kernel<<<dim3(BATCH), dim3(1024), 0, stream>>>(
        enc, h0, c0, Wo, bo, Ma2, v0, Wc2, bias_g,
        pred_out, hid_out, attn_out);
}

// Round 8
// 1325.067 us; speedup vs baseline: 4.5184x; 1.0230x over previous
//
#include <hip/hip_runtime.h>
#include <math.h>

#define HID   256
#define SEQ   512
#define BATCH 256
#define NPRED 64
#define NOUT  3
#define KP2   264    // fp16 k-pairs of padded xcat2: [x0,x1,x2,0, ctx(256), h(256), pad] / 2
#define GATES 1024

typedef unsigned int u32;
typedef _Float16 half2_t __attribute__((ext_vector_type(2)));
typedef __fp16   fp16x2_t __attribute__((ext_vector_type(2)));

__device__ __forceinline__ float sigmoidf_(float x) { return 1.0f / (1.0f + __expf(-x)); }
__device__ __forceinline__ float tanhf_(float x)    { return 1.0f - 2.0f / (__expf(2.0f * x) + 1.0f); }

// ---- fp16 pack / dot / pk helpers -----------------------------------------
__device__ __forceinline__ float fdot2_(u32 a, u32 b, float c) {
#if __has_builtin(__builtin_amdgcn_fdot2)
    union { u32 u; half2_t h; } x, y; x.u = a; y.u = b;
    return __builtin_amdgcn_fdot2(x.h, y.h, c, false);
#else
    union { u32 u; _Float16 h[2]; } x, y; x.u = a; y.u = b;
    return c + (float)x.h[0] * (float)y.h[0] + (float)x.h[1] * (float)y.h[1];
#endif
}
__device__ __forceinline__ u32 pkrtz_(float a, float b) {
#if __has_builtin(__builtin_amdgcn_cvt_pkrtz)
    union { fp16x2_t h; u32 u; } c; c.h = __builtin_amdgcn_cvt_pkrtz(a, b); return c.u;
#else
    union { _Float16 h[2]; u32 u; } c; c.h[0] = (_Float16)a; c.h[1] = (_Float16)b; return c.u;
#endif
}
__device__ __forceinline__ u32 pkrne_(float a, float b) {   // RNE pack
    union { _Float16 h[2]; u32 u; } c; c.h[0] = (_Float16)a; c.h[1] = (_Float16)b; return c.u;
}
__device__ __forceinline__ u32 pkfma_(u32 a, u32 b, u32 c) {  // v_pk_fma_f16
    union { u32 u; half2_t h; } x, y, z, r; x.u = a; y.u = b; z.u = c;
    r.h = x.h * y.h + z.h;
    return r.u;
}
__device__ __forceinline__ u32 pkadd_(u32 a, u32 b) {
    union { u32 u; half2_t h; } x, y, r; x.u = a; y.u = b;
    r.h = x.h + y.h;
    return r.u;
}
__device__ __forceinline__ float lof_(u32 u) {
    union { u32 x; half2_t h; } c; c.x = u; return (float)c.h[0];
}
__device__ __forceinline__ float hif_(u32 u) {
    union { u32 x; half2_t h; } c; c.x = u; return (float)c.h[1];
}

// ---------------------------------------------------------------------------
// prep_wc: Wcat column for padded-xcat2 k:
//   k<3: W_ih[:,k] (x_in) | k==3: 0 | 4<=k<260: W_ih[:,k-1] (ctx) |
//   260<=k<516: W_hh[:,k-260] (h) | else 0.  fp16 pairs, comp q = gate 4j+q.
// ---------------------------------------------------------------------------
__device__ __forceinline__ float colval_(const float* W_ih, const float* W_hh, int g, int k) {
    if (k < 3)   return W_ih[g * 259 + k];
    if (k == 3)  return 0.f;
    if (k < 260) return W_ih[g * 259 + (k - 1)];
    if (k < 516) return W_hh[g * HID + (k - 260)];
    return 0.f;
}
__global__ void prep_wc(const float* __restrict__ W_ih,
                        const float* __restrict__ W_hh,
                        uint4* __restrict__ Wc2) {
    const int p = blockIdx.x;        // 0..263 k-pair
    const int j = threadIdx.x;       // 0..255
    u32 comp[4];
    #pragma unroll
    for (int q = 0; q < 4; ++q) {
        const int g = 4 * j + q;
        comp[q] = pkrne_(colval_(W_ih, W_hh, g, 2 * p),
                         colval_(W_ih, W_hh, g, 2 * p + 1));
    }
    Wc2[p * 256 + j] = make_uint4(comp[0], comp[1], comp[2], comp[3]);
}

// ---------------------------------------------------------------------------
// prep_ma: MaT[k][j] = sum_m Wa[m][k]*Ua[m][j]; fp16 pairs.
// ---------------------------------------------------------------------------
__global__ void prep_ma(const float* __restrict__ Wa,
                        const float* __restrict__ Ua,
                        uint2* __restrict__ Ma2) {
    const int k4 = blockIdx.x;       // 0..63
    const int j  = threadIdx.x;      // 0..255
    float acc[4] = {0.f, 0.f, 0.f, 0.f};
    for (int m = 0; m < HID; ++m) {
        const float ua = Ua[m * HID + j];
        #pragma unroll
        for (int q = 0; q < 4; ++q)
            acc[q] += Wa[m * HID + 4 * k4 + q] * ua;
    }
    Ma2[k4 * 256 + j] = make_uint2(pkrne_(acc[0], acc[1]), pkrne_(acc[2], acc[3]));
}

__global__ void prep_misc(const float* __restrict__ b_ih,
                          const float* __restrict__ b_hh,
                          const float* __restrict__ ba,
                          const float* __restrict__ Ua,
                          float* __restrict__ bias_g,
                          float* __restrict__ v0) {
    const int t = threadIdx.x;
    if (t < GATES) bias_g[t] = b_ih[t] + b_hh[t];
    if (t < HID) {
        float acc = 0.f;
        for (int m = 0; m < HID; ++m) acc += ba[m] * Ua[m * HID + t];
        v0[t] = acc;
    }
}

// ---- P1: vq[j] = v0[j] + sum_k MaT[k][j] h[k]; Ma resident in LDS ---------
__device__ __forceinline__ void p1_body(const u32* s_ma,
                                        const float* __restrict__ v0,
                                        const u32* s_xh, u32* s_vqh, int j) {
    float a0 = 0.f, a1 = 0.f;
    #pragma unroll 8
    for (int p2 = 0; p2 < 64; ++p2) {
        const uint2 ma = *(const uint2*)&s_ma[(p2 << 9) + (j << 1)];
        const uint2 hh = *(const uint2*)&s_xh[130 + (p2 << 1)];
        a0 = fdot2_(ma.x, hh.x, a0);
        a1 = fdot2_(ma.y, hh.y, a1);
    }
    float acc = v0[j] + a0 + a1;
    const float accN = __shfl_xor(acc, 1);
    if (!(j & 1)) s_vqh[j >> 1] = pkrtz_(acc, accN);
}

// ---- Eh half: 32 h-part k-pairs starting at base + 32*ks2; 2-way split-K ---
// INIT=true: initialize slice 4+ks2 (G phase, rows 194..257 for next step).
// INIT=false: accumulate into slice 4+ks2 (D phase, rows 130..193, idle waves).
// Same thread writes/reads the same address in both phases -> no race.
template <bool INIT>
__device__ __forceinline__ void ehx_body(const uint4* __restrict__ Wc2,
                                         const u32* s_xh, float* s_gp,
                                         int j, int ks2, int base) {
    float4 g4;
    if (INIT) g4 = make_float4(0.f, 0.f, 0.f, 0.f);
    else      g4 = *(const float4*)&s_gp[((4 + ks2) << 10) + (j << 2)];
    const int pbeg = base + (ks2 << 5);
    #pragma unroll 4
    for (int pp = 0; pp < 32; ++pp) {
        const int p = pbeg + pp;
        const uint4 w = Wc2[(p << 8) + j];
        const u32 x = s_xh[p];
        g4.x = fdot2_(w.x, x, g4.x);
        g4.y = fdot2_(w.y, x, g4.y);
        g4.z = fdot2_(w.z, x, g4.z);
        g4.w = fdot2_(w.w, x, g4.w);
    }
    *(float4*)&s_gp[((4 + ks2) << 10) + (j << 2)] = g4;
}

// ---------------------------------------------------------------------------
// Persistent decoder: one 1024-thread block per batch element, 5 barriers/step.
// enc slice (512x256 fp16 = 256 KB) held ENTIRELY in registers.
// Ma (128 KB) resident in LDS.  Flash-style wave-local softmax.
// Weight stream split into THREE balanced windows (~32 loads/thread each):
//   D-phase (idle waves 8-15): Eh rows 130-193 accumulate into slices 4,5
//   Ec-phase (16 waves):       rows 0-129 -> slices 0-3
//   G-phase (waves 8-15):      Eh rows 194-257 (next step) init slices 4,5
// Valid because Eh only needs h (stable from F(n-1) through Ec(n)).
// All unrolls bounded <=8 (full unrolls spill encR: R4/R6 regressions).
// ---------------------------------------------------------------------------
__global__ __launch_bounds__(1024)
void decoder_kernel(const float* __restrict__ enc,     // [B,S,H] fp32
                    const float* __restrict__ h0,
                    const float* __restrict__ c0,
                    const float* __restrict__ Wo,      // [3,H]
                    const float* __restrict__ bo,      // [3]
                    const uint2* __restrict__ Ma2,     // [64][256]
                    const float* __restrict__ v0,      // [256]
                    const uint4* __restrict__ Wc2,     // [264][256]
                    const float* __restrict__ bias_g,  // [1024]
                    float* __restrict__ pred_out,      // [B,N,3]
                    float* __restrict__ hid_out,       // [B,H]
                    float* __restrict__ attn_out)      // [B,N,S]
{
    const int b    = blockIdx.x;
    const int t    = threadIdx.x;
    const int wave = t >> 6;
    const int lane = t & 63;
    const int rg   = t >> 4;          // 0..63 row group (8 rows each)
    const int hc   = t & 15;          // 0..15 h-chunk (16 cols = 8 pairs)
    const int jj   = t & 255;         // j index for gate slices

    __shared__ __align__(16) float s_h[HID];
    __shared__ __align__(16) u32   s_vqh[HID / 2];     // vq fp16 pairs
    __shared__ __align__(16) u32   s_xh[KP2];          // xcat2 fp16 pairs
    __shared__ __align__(16) float s_gp[6144];         // AC: u32[16][128] ctx partials
                                                       // (overlaps Ec slices 0-1);
                                                       // gate slices: Ec 0..3, Eh 4..5
    __shared__ __align__(16) float s_scores[SEQ];      // raw e (wave-max relative)
    __shared__ __align__(16) u32   s_ma[32768];        // Ma resident: 128 KB
    __shared__ __align__(16) float s_wmax[16], s_wsum[16], s_pred[4];
    u32* const s_gpu = (u32*)s_gp;

    // ---- load enc slice into registers (once), fp32 -> fp16 RNE ----
    u32 encR[64];
    {
        const float* ep = enc + ((size_t)b * SEQ + rg * 8) * HID + hc * 16;
        #pragma unroll
        for (int rr = 0; rr < 8; ++rr) {
            #pragma unroll
            for (int i2 = 0; i2 < 4; ++i2) {
                const float4 f = *(const float4*)(ep + rr * HID + i2 * 4);
                encR[rr * 8 + i2 * 2]     = pkrne_(f.x, f.y);
                encR[rr * 8 + i2 * 2 + 1] = pkrne_(f.z, f.w);
            }
        }
    }

    // ---- copy Ma2 global -> LDS (once) ----
    {
        const uint4* g4 = (const uint4*)Ma2;
        uint4* l4 = (uint4*)s_ma;
        #pragma unroll
        for (int i = 0; i < 8; ++i) l4[t + (i << 10)] = g4[t + (i << 10)];
    }

    // ---- init LDS state; c-state in registers (thread t<256 owns c[t]) ----
    float cR = 0.f;
    if (t < HID) {
        const float hv = h0[b * HID + t];
        s_h[t] = hv;
        cR = c0[b * HID + t];
        const float hN = __shfl_xor(hv, 1);
        if (!(t & 1)) s_xh[130 + (t >> 1)] = pkrtz_(hv, hN);
    }
    if (t < 2) s_xh[t] = 0u;                       // SOS x_in pairs
    if (t >= 258 && t < KP2) s_xh[t] = 0u;         // zero pad pairs
    if (t < 4) s_pred[t] = 0.f;
    __syncthreads();

    // ---- prologue: vq + Eh-high partials for step 0 ----
    if (wave >= 4 && wave < 8)      p1_body(s_ma, v0, s_xh, s_vqh, jj);
    else if (wave >= 8)             ehx_body<true>(Wc2, s_xh, s_gp, jj, (t >> 8) - 2, 194);
    __syncthreads();

    for (int n = 0; n < NPRED; ++n) {
        // ---- [AC] scores + wave-local softmax + ctx partials ----
        float acc[8];
        {
            u32 vq[8];
            *(uint4*)&vq[0] = *(const uint4*)&s_vqh[hc * 8];
            *(uint4*)&vq[4] = *(const uint4*)&s_vqh[hc * 8 + 4];
            #pragma unroll
            for (int rr = 0; rr < 8; ++rr) {
                float a = 0.f;
                #pragma unroll
                for (int i = 0; i < 8; ++i) a = fdot2_(encR[rr * 8 + i], vq[i], a);
                acc[rr] = a;
            }
        }
        // reduce across the 16 h-chunk lanes (offsets 1..8)
        #pragma unroll
        for (int rr = 0; rr < 8; ++rr) {
            acc[rr] += __shfl_xor(acc[rr], 1);
            acc[rr] += __shfl_xor(acc[rr], 2);
            acc[rr] += __shfl_xor(acc[rr], 4);
            acc[rr] += __shfl_xor(acc[rr], 8);
        }
        // wave max (32 rows per wave)
        float mx = acc[0];
        #pragma unroll
        for (int rr = 1; rr < 8; ++rr) mx = fmaxf(mx, acc[rr]);
        mx = fmaxf(mx, __shfl_xor(mx, 16));
        mx = fmaxf(mx, __shfl_xor(mx, 32));
        if (lane == 0) s_wmax[wave] = mx;

        // exp relative to WAVE max; wave sum; stash raw e; ctx partials
        {
            float e[8];
            #pragma unroll
            for (int rr = 0; rr < 8; ++rr) e[rr] = __expf(acc[rr] - mx);
            float su = e[0];
            #pragma unroll
            for (int rr = 1; rr < 8; ++rr) su += e[rr];
            su += __shfl_xor(su, 16);
            su += __shfl_xor(su, 32);
            if (lane == 0) s_wsum[wave] = su;
            if (hc == 0) {
                #pragma unroll
                for (int rr = 0; rr < 8; ++rr) s_scores[rg * 8 + rr] = e[rr];
            }
            u32 ah[8];
            #pragma unroll
            for (int i = 0; i < 8; ++i) ah[i] = 0u;
            #pragma unroll
            for (int rr = 0; rr < 8; ++rr) {
                const u32 wp = pkrne_(e[rr], e[rr]);   // raw weights; scaling in D
                #pragma unroll
                for (int i = 0; i < 8; ++i)
                    ah[i] = pkfma_(encR[rr * 8 + i], wp, ah[i]);
            }
            #pragma unroll
            for (int i = 0; i < 8; ++i) {
                u32 v = ah[i];
                v = pkadd_(v, (u32)__shfl_xor((int)v, 16));
                v = pkadd_(v, (u32)__shfl_xor((int)v, 32));
                ah[i] = v;
            }
            if ((lane >> 4) == 0) {
                *(uint4*)&s_gpu[wave * 128 + hc * 8]     = *(const uint4*)&ah[0];
                *(uint4*)&s_gpu[wave * 128 + hc * 8 + 4] = *(const uint4*)&ah[4];
            }
        }
        __syncthreads();                                     // b3

        // ---- [D] waves 0-7: global max/L, ctx combine, attn, x_in;
        //      waves 8-15 (idle here): Eh rows 130-193 accumulate ----
        if (t < 512) {
            float M;
            {
                const float4* q4 = (const float4*)s_wmax;
                float4 v = q4[0];
                M = fmaxf(fmaxf(v.x, v.y), fmaxf(v.z, v.w));
                #pragma unroll
                for (int w = 1; w < 4; ++w) {
                    v = q4[w];
                    M = fmaxf(M, fmaxf(fmaxf(v.x, v.y), fmaxf(v.z, v.w)));
                }
            }
            float L = 0.f;
            #pragma unroll
            for (int w = 0; w < 16; ++w)
                L += __expf(s_wmax[w] - M) * s_wsum[w];
            const float invL = 1.0f / L;
            // coalesced attention write: one row element per thread
            attn_out[((size_t)b * NPRED + n) * SEQ + t] =
                s_scores[t] * (__expf(s_wmax[t >> 5] - M) * invL);
            if (t < 128) {
                float cx = 0.f, cy = 0.f;
                #pragma unroll
                for (int w = 0; w < 16; ++w) {
                    const float f = __expf(s_wmax[w] - M);
                    const u32 u = s_gpu[w * 128 + t];
                    cx += f * lof_(u);
                    cy += f * hif_(u);
                }
                s_xh[2 + t] = pkrne_(cx * invL, cy * invL);
            }
            if (t == 256) {
                s_xh[0] = pkrtz_(s_pred[0], s_pred[1]);
                s_xh[1] = pkrtz_(s_pred[2], 0.f);
            }
        } else {
            ehx_body<false>(Wc2, s_xh, s_gp, jj, (t >> 8) - 2, 130);
        }
        __syncthreads();                                     // b4

        // ---- [Ec] gate partials over x_in+ctx k-pairs 0..129; 4-way split ----
        {
            const int ks = t >> 8;
            const int pbeg = (ks < 2) ? 33 * ks : 66 + 32 * (ks - 2);
            const int pend = pbeg + ((ks < 2) ? 33 : 32);
            float4 g4 = {0.f, 0.f, 0.f, 0.f};
            #pragma unroll 4
            for (int p = pbeg; p < pend; ++p) {
                const uint4 w = Wc2[(p << 8) + jj];
                const u32 x = s_xh[p];
                g4.x = fdot2_(w.x, x, g4.x);
                g4.y = fdot2_(w.y, x, g4.y);
                g4.z = fdot2_(w.z, x, g4.z);
                g4.w = fdot2_(w.w, x, g4.w);
            }
            *(float4*)&s_gp[(ks << 10) + (jj << 2)] = g4;
        }
        __syncthreads();                                     // b5

        // ---- [F] gates finalize (6 slices) + LSTM pointwise; pack new h ----
        if (t < HID) {
            float gv[4];
            #pragma unroll
            for (int q = 0; q < 4; ++q) {
                const int gi = (q << 8) + t;
                gv[q] = bias_g[gi] + s_gp[gi] + s_gp[1024 + gi]
                      + s_gp[2048 + gi] + s_gp[3072 + gi]
                      + s_gp[4096 + gi] + s_gp[5120 + gi];
            }
            const float cn = sigmoidf_(gv[1]) * cR + sigmoidf_(gv[0]) * tanhf_(gv[2]);
            const float hn = sigmoidf_(gv[3]) * tanhf_(cn);
            cR = cn;
            s_h[t] = hn;
            const float hN = __shfl_xor(hn, 1);
            if (!(t & 1)) s_xh[130 + (t >> 1)] = pkrtz_(hn, hN);
        }
        __syncthreads();                                     // b6

        // ---- [G] pred (waves 0-2) || vq p1 from LDS (waves 4-7) ||
        //          Eh rows 194-257 for NEXT step (waves 8-15, init) ----
        if (wave < NOUT) {
            const float4 w4 = *(const float4*)&Wo[wave * HID + (lane << 2)];
            const float4 h4 = *(const float4*)&s_h[lane << 2];
            float p = w4.x * h4.x + w4.y * h4.y + w4.z * h4.z + w4.w * h4.w;
            #pragma unroll
            for (int off = 32; off >= 1; off >>= 1) p += __shfl_xor(p, off);
            if (lane == 0) {
                p += bo[wave];
                s_pred[wave] = p;
                pred_out[((size_t)b * NPRED + n) * NOUT + wave] = p;
            }
        } else if (wave >= 4 && wave < 8) {
            if (n + 1 < NPRED) p1_body(s_ma, v0, s_xh, s_vqh, jj);
        } else if (wave >= 8) {
            if (n + 1 < NPRED) ehx_body<true>(Wc2, s_xh, s_gp, jj, (t >> 8) - 2, 194);
        }
        __syncthreads();                                     // b7
    }

    if (t < HID) hid_out[b * HID + t] = s_h[t];
}

// ---------------------------------------------------------------------------
extern "C" void kernel_launch(void* const* d_in, const int* in_sizes, int n_in,
                              void* d_out, int out_size, void* d_ws, size_t ws_size,
                              hipStream_t stream) {
    const float* enc  = (const float*)d_in[0];
    const float* h0   = (const float*)d_in[1];
    const float* c0   = (const float*)d_in[2];
    const float* Wa   = (const float*)d_in[3];
    const float* ba   = (const float*)d_in[4];
    const float* Ua   = (const float*)d_in[5];
    // d_in[6] = bua: dropped — its score contribution is constant over s (softmax-invariant)
    const float* W_ih = (const float*)d_in[7];
    const float* W_hh = (const float*)d_in[8];
    const float* b_ih = (const float*)d_in[9];
    const float* b_hh = (const float*)d_in[10];
    const float* Wo   = (const float*)d_in[11];
    const float* bo   = (const float*)d_in[12];

    char* ws = (char*)d_ws;
    uint4* Wc2    = (uint4*)ws;                      ws += (size_t)KP2 * 256 * 16;  // 1,081,344
    uint2* Ma2    = (uint2*)ws;                      ws += (size_t)64 * 256 * 8;    //   131,072
    float* v0     = (float*)ws;                      ws += 256 * 4;
    float* bias_g = (float*)ws;                      ws += GATES * 4;
    (void)ws_size;

    float* pred_out = (float*)d_out;                    // [B,N,3]
    float* hid_out  = pred_out + BATCH * NPRED * NOUT;  // [1,B,H]
    float* attn_out = hid_out + BATCH * HID;            // [B,N,S]

    prep_wc  <<<dim3(KP2), dim3(256),  0, stream>>>(W_ih, W_hh, Wc2);
    prep_ma  <<<dim3(64),  dim3(256),  0, stream>>>(Wa, Ua, Ma2);
    prep_misc<<<dim3(1),   dim3(1024), 0, stream>>>(b_ih, b_hh, ba, Ua, bias_g, v0);
    decoder_kernel<<<dim3(BATCH), dim3(1024), 0, stream>>>(
        enc, h0, c0, Wo, bo, Ma2, v0, Wc2, bias_g,
        pred_out, hid_out, attn_out);
}